// Round 4
// baseline (61.435 us; speedup 1.0000x reference)
//
#include <hip/hip_runtime.h>

// CapsNet dynamic routing, fully fused, MFMA edition.
// u = x@W never materialized:  sum_i c[j,i]*u = ((sum_i c[j,i]*x[i,:]) @ W_j,
// o.u = x.(W_j@o). R4: the c/wt broadcast inner products (LDS-BW bound, ~21us
// of DS traffic) become mfma_f32_16x16x32_bf16; blog lives in MFMA C-regs.
//
//  PB (r=1,2): blogT[j][i] += wtT(A,[16][32]bf16) @ xrows(B, global->bf16)
//              softmax over j: 4 regs + shfl_xor(16,32); c -> cT bf16 LDS
//  PA: y[j][k] = cT(A) @ xT(B), K=512 split 2 K-steps/wave, tree-reduced
//  S : 160 thr, f32, y@W_j + squash (global W, L2-resident)
//  WT: 320 thr, f32, wt=W_j@o -> wtT bf16
// r=0: c uniform -> y0 = 0.1*colsum(x), computed in f32 during staging.

#define NI 512
#define NK 32
#define NJ 10
#define NT 512

#define XT_STRIDE 536   // bf16/row, 1072B: 16B-aligned, de-banked
#define CT_STRIDE 520   // bf16/row, 1040B: 16B-aligned
#define YBP_STRIDE 520  // f32/wave-row

typedef __attribute__((ext_vector_type(8))) short short8;
typedef __attribute__((ext_vector_type(4))) float f32x4;

__device__ __forceinline__ short f2bf(float f) {   // RNE f32->bf16
    unsigned u = __float_as_uint(f);
    unsigned r = (u + 0x7FFFu + ((u >> 16) & 1u)) >> 16;
    return (short)r;
}

__global__ __launch_bounds__(NT, 2) void capsnet_kernel(
    const float* __restrict__ x, const float* __restrict__ W,
    float* __restrict__ out)
{
    __shared__ __attribute__((aligned(16))) short xT[32 * XT_STRIDE];   // 34,304 B  xT[k][i] bf16
    __shared__ __attribute__((aligned(16))) short cT[16 * CT_STRIDE];   // 16,640 B  cT[j][i] bf16
    __shared__ __attribute__((aligned(16))) short wtb[16 * 32];         //  1,024 B  wtT[j][k] bf16
    __shared__ __attribute__((aligned(16))) float ybp[8 * YBP_STRIDE];  // 16,640 B  per-wave y partials (r0: scr)
    __shared__ float yb[512];                                           //  2,048 B  y[t][j][kl]
    __shared__ float ob[160];
    __shared__ float lg[NJ];

    const int tid  = threadIdx.x;
    const int b    = blockIdx.x;
    const int lane = tid & 63;
    const int w    = tid >> 6;        // wave 0..7
    const int l15  = lane & 15;
    const int lg4  = lane >> 4;       // lane group 0..3
    const int k0   = lg4 << 3;        // fragment k-offset (8 elems/lane)

    const float* xg = x + (size_t)b * (NI * NK);
    float* scr = ybp;                 // r0 colsum scratch overlays ybp

    // ---- stage: coalesced f32 read -> colsum partials + bf16 transpose to xT ----
    {
        const float4* xb4 = reinterpret_cast<const float4*>(xg);
        float4 s4 = make_float4(0.f, 0.f, 0.f, 0.f);
        const int kq  = tid & 7;
        const int kk0 = kq << 2;
        #pragma unroll
        for (int r = 0; r < 8; ++r) {
            const int idx = tid + r * NT;
            const float4 v = xb4[idx];
            const int i = idx >> 3;                  // row of x
            s4.x += v.x; s4.y += v.y; s4.z += v.z; s4.w += v.w;
            xT[(kk0 + 0) * XT_STRIDE + i] = f2bf(v.x);
            xT[(kk0 + 1) * XT_STRIDE + i] = f2bf(v.y);
            xT[(kk0 + 2) * XT_STRIDE + i] = f2bf(v.z);
            xT[(kk0 + 3) * XT_STRIDE + i] = f2bf(v.w);
        }
        *reinterpret_cast<float4*>(&scr[(kq << 8) + ((tid >> 3) << 2)]) = s4;
    }
    __syncthreads();

    // ---- r0: y0[j][k] = 0.1 * colsum[k]  (f32-exact) ----
    if (tid < 32) {
        const int kq = tid >> 2, c = tid & 3;
        float s = 0.f;
        #pragma unroll
        for (int t = 0; t < 64; ++t) s += scr[(kq << 8) + (t << 2) + c];
        s *= 0.1f;
        const int t16 = tid >> 4, kl = tid & 15;
        #pragma unroll
        for (int j = 0; j < NJ; ++j) yb[t16 * 256 + j * 16 + kl] = s;
    }
    __syncthreads();

    f32x4 blogA[4];                   // blogT fragments: row j=(lg4*4+r), col i=16t+l15
    #pragma unroll
    for (int t = 0; t < 4; ++t) blogA[t] = (f32x4){0.f, 0.f, 0.f, 0.f};

    for (int r = 0; r < 3; ++r) {
        if (r > 0) {
            // ===== PB: blogT += wtT(A) @ x(B); softmax_j -> cT =====
            const short8 afrag = *reinterpret_cast<const short8*>(&wtb[l15 * 32 + k0]);
            #pragma unroll
            for (int t = 0; t < 4; ++t) {
                const int i = (w << 6) + (t << 4) + l15;
                const float4 v0 = *reinterpret_cast<const float4*>(xg + i * NK + k0);
                const float4 v1 = *reinterpret_cast<const float4*>(xg + i * NK + k0 + 4);
                short8 bfrag;
                bfrag[0] = f2bf(v0.x); bfrag[1] = f2bf(v0.y);
                bfrag[2] = f2bf(v0.z); bfrag[3] = f2bf(v0.w);
                bfrag[4] = f2bf(v1.x); bfrag[5] = f2bf(v1.y);
                bfrag[6] = f2bf(v1.z); bfrag[7] = f2bf(v1.w);
                blogA[t] = __builtin_amdgcn_mfma_f32_16x16x32_bf16(afrag, bfrag, blogA[t], 0, 0, 0);
            }
            const int jbase = lg4 << 2;
            #pragma unroll
            for (int t = 0; t < 4; ++t) {
                const f32x4 bv = blogA[t];
                const float v0 = (jbase + 0 < NJ) ? bv[0] : -1e30f;
                const float v1 = (jbase + 1 < NJ) ? bv[1] : -1e30f;
                const float v2 = (jbase + 2 < NJ) ? bv[2] : -1e30f;
                const float v3 = (jbase + 3 < NJ) ? bv[3] : -1e30f;
                float m = fmaxf(fmaxf(v0, v1), fmaxf(v2, v3));
                m = fmaxf(m, __shfl_xor(m, 16));
                m = fmaxf(m, __shfl_xor(m, 32));
                const float e0 = __expf(v0 - m), e1 = __expf(v1 - m);
                const float e2 = __expf(v2 - m), e3 = __expf(v3 - m);
                float ssum = e0 + e1 + e2 + e3;
                ssum += __shfl_xor(ssum, 16);
                ssum += __shfl_xor(ssum, 32);
                const float inv = 1.f / ssum;
                const int i = (w << 6) + (t << 4) + l15;
                cT[(jbase + 0) * CT_STRIDE + i] = f2bf(e0 * inv);   // pad rows j>=10: e=0 -> c=0
                cT[(jbase + 1) * CT_STRIDE + i] = f2bf(e1 * inv);
                cT[(jbase + 2) * CT_STRIDE + i] = f2bf(e2 * inv);
                cT[(jbase + 3) * CT_STRIDE + i] = f2bf(e3 * inv);
            }
            __syncthreads();

            // ===== PA: y[j][k] partials, wave w does K-steps s=2w,2w+1 =====
            {
                f32x4 yfrag[2];
                #pragma unroll
                for (int t = 0; t < 2; ++t) yfrag[t] = (f32x4){0.f, 0.f, 0.f, 0.f};
                #pragma unroll
                for (int ss = 0; ss < 2; ++ss) {
                    const int s = (w << 1) + ss;
                    const short8 ca = *reinterpret_cast<const short8*>(
                        &cT[l15 * CT_STRIDE + (s << 5) + k0]);
                    #pragma unroll
                    for (int t = 0; t < 2; ++t) {
                        const short8 xb = *reinterpret_cast<const short8*>(
                            &xT[((t << 4) + l15) * XT_STRIDE + (s << 5) + k0]);
                        yfrag[t] = __builtin_amdgcn_mfma_f32_16x16x32_bf16(ca, xb, yfrag[t], 0, 0, 0);
                    }
                }
                #pragma unroll
                for (int t = 0; t < 2; ++t)
                    #pragma unroll
                    for (int rr = 0; rr < 4; ++rr)
                        ybp[w * YBP_STRIDE + t * 256 + ((lg4 << 2) + rr) * 16 + l15] = yfrag[t][rr];
            }
            __syncthreads();
            // deterministic 8-wave tree reduce
            {
                float s = 0.f;
                #pragma unroll
                for (int ww = 0; ww < 8; ++ww) s += ybp[ww * YBP_STRIDE + tid];
                yb[tid] = s;
            }
            __syncthreads();
        }

        // ===== S: s[j][d] = y[j]@W_j col d; squash -> o (r==2: logits) =====
        if (tid < 160) {
            const int j = tid >> 4, d = tid & 15;
            float s = 0.f;
            #pragma unroll
            for (int kk = 0; kk < NK; ++kk)
                s = fmaf(yb[(kk >> 4) * 256 + j * 16 + (kk & 15)], W[kk * 160 + j * 16 + d], s);
            float sq = s * s;
            sq += __shfl_xor(sq, 1); sq += __shfl_xor(sq, 2);
            sq += __shfl_xor(sq, 4); sq += __shfl_xor(sq, 8);
            const float scale = (sq / (1.f + sq)) / sqrtf(sq + 1e-7f);
            const float o_ = s * scale;
            if (r < 2) {
                ob[tid] = o_;
            } else {
                float ss2 = o_;
                ss2 += __shfl_xor(ss2, 1); ss2 += __shfl_xor(ss2, 2);
                ss2 += __shfl_xor(ss2, 4); ss2 += __shfl_xor(ss2, 8);
                if (d == 0) lg[j] = ss2;
            }
        }
        __syncthreads();

        if (r < 2) {
            // ===== WT: wtT[j][k] = W_j-row(k) . o[j] -> bf16 =====
            if (tid < 320) {
                const int j = tid >> 5, kk = tid & 31;
                const float4* W4 = reinterpret_cast<const float4*>(W + kk * 160 + j * 16);
                const float4* o4 = reinterpret_cast<const float4*>(&ob[j * 16]);
                float s = 0.f;
                #pragma unroll
                for (int q = 0; q < 4; ++q) {
                    const float4 wv = W4[q]; const float4 ov = o4[q];
                    s += wv.x * ov.x + wv.y * ov.y + wv.z * ov.z + wv.w * ov.w;
                }
                wtb[j * 32 + kk] = f2bf(s);
            }
            __syncthreads();
        }
    }

    // ---- final: softmax over J of logits ----
    if (tid == 0) {
        float m = -1e30f;
        #pragma unroll
        for (int j = 0; j < NJ; ++j) m = fmaxf(m, lg[j]);
        float e[NJ]; float sum = 0.f;
        #pragma unroll
        for (int j = 0; j < NJ; ++j) { e[j] = __expf(lg[j] - m); sum += e[j]; }
        const float inv = 1.f / sum;
        #pragma unroll
        for (int j = 0; j < NJ; ++j) out[b * NJ + j] = e[j] * inv;
    }
}

extern "C" void kernel_launch(void* const* d_in, const int* in_sizes, int n_in,
                              void* d_out, int out_size, void* d_ws, size_t ws_size,
                              hipStream_t stream) {
    (void)in_sizes; (void)n_in; (void)d_ws; (void)ws_size; (void)out_size;
    const float* x = (const float*)d_in[0];
    const float* W = (const float*)d_in[1];
    float* out = (float*)d_out;
    hipLaunchKernelGGL(capsnet_kernel, dim3(512), dim3(NT), 0, stream, x, W, out);
}